// Round 8
// baseline (99.293 us; speedup 1.0000x reference)
//
#include <hip/hip_runtime.h>

// Problem constants (fixed by setup_inputs)
#define B_   4
#define C_   256
#define H_   96
#define W_   128
#define F_   9
#define G_   4
#define CG   64            // channels per group
#define NC4  16            // channel QUADS per group
#define NO   81            // offsets
#define HW_  (H_ * W_)

// Per-pass geometry: ONE dy per pass (9 passes), 4 output rows, 2 px/thread
#define TROWS 4                  // tile rows = output rows (no row halo for fixed dy)
#define TCOLS 144                // 128 + 16 halo cols
#define HCOL2 72                 // cols per parity
#define PTE   (TROWS * TCOLS)    // 576 entries (8B: 4ch f16)
#define NCH   3                  // staging chunks 256+256+64

typedef _Float16 half2v __attribute__((ext_vector_type(2)));
typedef unsigned u32x2 __attribute__((ext_vector_type(2)));
typedef unsigned u32x4 __attribute__((ext_vector_type(4)));

__device__ __forceinline__ half2v u2h(unsigned u) {
    half2v h; __builtin_memcpy(&h, &u, 4); return h;
}
__device__ __forceinline__ unsigned h2u(half2v h) {
    unsigned u; __builtin_memcpy(&u, &h, 4); return u;
}
__device__ __forceinline__ half2v pkrtz(float a, float b) {
    auto r = __builtin_amdgcn_cvt_pkrtz(a, b);
    half2v h; __builtin_memcpy(&h, &r, 4); return h;
}
__device__ __forceinline__ unsigned pkrtz_u(float a, float b) {
    auto r = __builtin_amdgcn_cvt_pkrtz(a, b);
    unsigned u; __builtin_memcpy(&u, &r, 4); return u;
}

#if __has_builtin(__builtin_amdgcn_fdot2)
#define FDOT2(a, b, c) __builtin_amdgcn_fdot2((a), (b), (c), false)
#else
__device__ __forceinline__ float fdot2_fb(half2v a, half2v b, float c) {
    return c + (float)a[0] * (float)b[0] + (float)a[1] * (float)b[1];
}
#define FDOT2(a, b, c) fdot2_fb((a), (b), (c))
#endif

// Pack weights [C,9,9] f32 -> [g][c4][o] as 4-channel (2x f16x2) in d_ws
__global__ void pack_weights_kernel(const float* __restrict__ w,
                                    u32x2* __restrict__ wp) {
    int i = blockIdx.x * blockDim.x + threadIdx.x;
    if (i >= G_ * NC4 * NO) return;
    int o  = i % NO;
    int c4 = (i / NO) % NC4;
    int g  = i / (NO * NC4);
    const float* base = w + (size_t)(g * CG + 4 * c4) * NO + o;
    u32x2 r;
    r.x = pkrtz_u(base[0], base[NO]);
    r.y = pkrtz_u(base[2 * NO], base[3 * NO]);
    wp[i] = r;
}

template <bool PACKED>
__global__ __launch_bounds__(256)
void wcorr_kernel(const float* __restrict__ in1, const float* __restrict__ in2,
                  const u32x2* __restrict__ wp, const float* __restrict__ wraw,
                  float* __restrict__ out) {
    // parity-split entries: flat = (row*2 + parity)*HCOL2 + col2
    __shared__ u32x2 tile[2][PTE];   // 9,216 B

    // grid = 16 pairs x 9 dy x 24 hblks = 3456 blocks
    // XCD-aware: (b,g) pair constant per XCD chunk -> in2 plane stays in XCD L2
    int bid  = blockIdx.x;
    int xcd  = bid & 7;
    int slot = bid >> 3;                 // 0..431
    int pair = xcd + 8 * (slot / 216);   // 0..15  == b*4+g
    int rem  = slot % 216;
    int dy   = rem / 24;                 // 0..8
    int hblk = rem % 24;
    int b = pair >> 2, g = pair & 3;
    int h0 = hblk * TROWS;

    int t = threadIdx.x;
    int r = t >> 6;                 // 0..3 output row within tile (= wave id)
    int k = t & 63;
    int p   = k & 1;                // pixel parity
    int w02 = (k >> 1) * 2;         // even parity-col base
    int w0  = 4 * (k >> 1) + p;     // first pixel col; second = w0+2

    const float* in1g = in1 + (size_t)(b * C_ + g * CG) * HW_;
    const float* in2g = in2 + (size_t)(b * C_ + g * CG) * HW_;

    // ---- staging geometry (c4-invariant): clamp + mask, no per-lane branch ----
    const int gr0 = h0 + 2 * dy - 8;     // tap row for tile row 0
    int po[NCH]; unsigned msk[NCH]; int lix[NCH];
#pragma unroll
    for (int c = 0; c < NCH; ++c) {
        int e    = c * 256 + t;
        int row  = e / TCOLS;
        int hcol = e - row * TCOLS;
        int gr = gr0 + row, gc = hcol - 8;
        bool inb = (e < PTE) && gr >= 0 && gr < H_ && gc >= 0 && gc < W_;
        int off = gr * W_ + gc;
        off = off < 0 ? 0 : (off > HW_ - 1 ? HW_ - 1 : off);
        po[c]  = off;
        float m = inb ? 1.f : 0.f;
        msk[c] = pkrtz_u(m, m);
        lix[c] = (row * 2 + (hcol & 1)) * HCOL2 + (hcol >> 1);
    }

    float acc[18];
#pragma unroll
    for (int o = 0; o < 18; ++o) acc[o] = 0.f;

    // ---- prologue: stage c4=0 into tile[0] ----
    {
#pragma unroll
        for (int c = 0; c < NCH; ++c) {
            if (c < 2 || t < PTE - 512) {       // chunk2: wave 0 only (uniform)
                const float* q = in2g + po[c];
                half2v m = u2h(msk[c]);
                u32x2 rr;
                rr.x = h2u(u2h(pkrtz_u(q[0], q[HW_])) * m);
                rr.y = h2u(u2h(pkrtz_u(q[2 * HW_], q[3 * HW_])) * m);
                tile[0][lix[c]] = rr;
            }
        }
    }

    const int in1off = (h0 + r) * W_ + w0;      // pixel 0; pixel 1 = +2

    for (int c4 = 0; c4 < NC4; ++c4) {
        const bool more = (c4 + 1 < NC4);

        // in1 loads for THIS c4 (latency hides under barrier + stage writes)
        const float* ib = in1g + (size_t)(4 * c4) * HW_ + in1off;
        float a00 = ib[0],        a01 = ib[HW_],
              a02 = ib[2 * HW_],  a03 = ib[3 * HW_];
        float a10 = ib[2],        a11 = ib[HW_ + 2],
              a12 = ib[2 * HW_ + 2], a13 = ib[3 * HW_ + 2];

        // next tile's global loads issued BEFORE the barrier
        float v0[NCH], v1[NCH], v2[NCH], v3[NCH];
        if (more) {
            const float* chb = in2g + (size_t)(4 * (c4 + 1)) * HW_;
#pragma unroll
            for (int c = 0; c < NCH; ++c) {
                if (c < 2 || t < PTE - 512) {
                    const float* q = chb + po[c];
                    v0[c] = q[0]; v1[c] = q[HW_];
                    v2[c] = q[2 * HW_]; v3[c] = q[3 * HW_];
                }
            }
        }

        __syncthreads();    // tile[c4&1] ready; readers done with other buffer

        if (more) {
            u32x2* dst = tile[(c4 + 1) & 1];
#pragma unroll
            for (int c = 0; c < NCH; ++c) {
                if (c < 2 || t < PTE - 512) {
                    half2v m = u2h(msk[c]);
                    u32x2 rr;
                    rr.x = h2u(u2h(pkrtz_u(v0[c], v1[c])) * m);
                    rr.y = h2u(u2h(pkrtz_u(v2[c], v3[c])) * m);
                    dst[lix[c]] = rr;
                }
            }
        }

        const u32x2* lt = tile[c4 & 1];
        half2v ha0 = pkrtz(a00, a01), hb0 = pkrtz(a02, a03);
        half2v ha1 = pkrtz(a10, a11), hb1 = pkrtz(a12, a13);

        // 5x ds_read_b128: entries w02..w02+9 of this thread's (row,parity)
        const u32x4* lb = (const u32x4*)(lt + (r * 2 + p) * HCOL2 + w02);
        u32x4 E[5];
#pragma unroll
        for (int j = 0; j < 5; ++j) E[j] = lb[j];

        const u32x2* wrow = PACKED ? (wp + ((size_t)g * NC4 + c4) * NO + dy * F_) : nullptr;
        const float* wr = wraw + (size_t)(g * CG + 4 * c4) * NO + dy * F_;

#pragma unroll
        for (int dx = 0; dx < F_; ++dx) {
            half2v wa, wb;
            if (PACKED) {
                u32x2 wv = wrow[dx];            // wave-uniform -> s_load
                wa = u2h(wv.x); wb = u2h(wv.y);
            } else {
                wa = pkrtz(wr[dx], wr[dx + NO]);
                wb = pkrtz(wr[dx + 2 * NO], wr[dx + 3 * NO]);
            }
            // pixel 0: entry m0 = dx ; pixel 1: entry m1 = dx+1
            {
                const int m0 = dx;
                unsigned lo = (m0 & 1) ? E[m0 >> 1].z : E[m0 >> 1].x;
                unsigned hi = (m0 & 1) ? E[m0 >> 1].w : E[m0 >> 1].y;
                float s = FDOT2(wa * ha0, u2h(lo), acc[dx]);
                acc[dx] = FDOT2(wb * hb0, u2h(hi), s);
            }
            {
                const int m1 = dx + 1;
                unsigned lo = (m1 & 1) ? E[m1 >> 1].z : E[m1 >> 1].x;
                unsigned hi = (m1 & 1) ? E[m1 >> 1].w : E[m1 >> 1].y;
                float s = FDOT2(wa * ha1, u2h(lo), acc[9 + dx]);
                acc[9 + dx] = FDOT2(wb * hb1, u2h(hi), s);
            }
        }
    }

    // out[b][g*81 + dy*9 + dx][h][w] for both pixels
    size_t obase = (((size_t)(pair * NO + dy * F_)) * H_ + (h0 + r)) * W_ + w0;
#pragma unroll
    for (int dx = 0; dx < F_; ++dx) {
        out[obase + (size_t)dx * HW_]     = acc[dx];
        out[obase + (size_t)dx * HW_ + 2] = acc[9 + dx];
    }
}

extern "C" void kernel_launch(void* const* d_in, const int* in_sizes, int n_in,
                              void* d_out, int out_size, void* d_ws, size_t ws_size,
                              hipStream_t stream) {
    const float* in1  = (const float*)d_in[0];
    const float* in2  = (const float*)d_in[1];
    const float* wraw = (const float*)d_in[2];
    float* out = (float*)d_out;

    const size_t wp_bytes = (size_t)G_ * NC4 * NO * 8;  // 41,472 B
    const int nblocks = 16 * F_ * (H_ / TROWS);         // 16*9*24 = 3456

    if (ws_size >= wp_bytes) {
        u32x2* wp = (u32x2*)d_ws;
        int n = G_ * NC4 * NO;
        pack_weights_kernel<<<(n + 255) / 256, 256, 0, stream>>>(wraw, wp);
        wcorr_kernel<true><<<nblocks, 256, 0, stream>>>(in1, in2, wp, wraw, out);
    } else {
        wcorr_kernel<false><<<nblocks, 256, 0, stream>>>(in1, in2, nullptr, wraw, out);
    }
}